// Round 1
// baseline (41.670 us; speedup 1.0000x reference)
//
#include <hip/hip_runtime.h>

// LatencyEncoder: out[b, t, n] = (t == floor(clip(-TAU*log(sigmoid(x[b,n])+EPS), 0, T-1))) ? 1 : 0
// B=256, N=4096, T=64. Output 256 MiB fp32 -> write-BW bound (~43 us floor at 6.3 TB/s).

#define B_DIM 256
#define N_DIM 4096
#define T_DIM 64

__global__ __launch_bounds__(256) void latency_encoder_kernel(
    const float* __restrict__ x, float* __restrict__ out)
{
    const int b  = blockIdx.y;
    const int n0 = (blockIdx.x * 256 + threadIdx.x) * 4;  // 4 consecutive n per thread

    // Load 4 inputs (coalesced 16B/lane)
    const float4 xv = *reinterpret_cast<const float4*>(x + (size_t)b * N_DIM + n0);
    const float xs[4] = {xv.x, xv.y, xv.z, xv.w};

    // Compute spike time in double precision so floor() decisions match the
    // float64 numpy reference (f32 transcendental ULP noise near integer
    // boundaries would flip one-hot bins -> absmax 1.0 failure).
    int t[4];
#pragma unroll
    for (int i = 0; i < 4; ++i) {
        const double s   = 1.0 / (1.0 + exp(-(double)xs[i]));
        double lat = -10.0 * log(s + 1e-7);
        lat = lat < 0.0 ? 0.0 : (lat > 63.0 ? 63.0 : lat);
        t[i] = (int)lat;  // lat >= 0, trunc == floor
    }

    // Write the one-hot time series: 64 coalesced float4 stores per thread.
    float4* outp = reinterpret_cast<float4*>(out + (size_t)b * (T_DIM * N_DIM) + n0);
#pragma unroll
    for (int tt = 0; tt < T_DIM; ++tt) {
        float4 v;
        v.x = (tt == t[0]) ? 1.0f : 0.0f;
        v.y = (tt == t[1]) ? 1.0f : 0.0f;
        v.z = (tt == t[2]) ? 1.0f : 0.0f;
        v.w = (tt == t[3]) ? 1.0f : 0.0f;
        outp[(size_t)tt * (N_DIM / 4)] = v;
    }
}

extern "C" void kernel_launch(void* const* d_in, const int* in_sizes, int n_in,
                              void* d_out, int out_size, void* d_ws, size_t ws_size,
                              hipStream_t stream)
{
    const float* x = (const float*)d_in[0];
    float* out = (float*)d_out;

    // 4096 n / (256 threads * 4 per thread) = 4 blocks per row, 256 rows.
    dim3 grid(N_DIM / (256 * 4), B_DIM);
    latency_encoder_kernel<<<grid, 256, 0, stream>>>(x, out);
}